// Round 14
// baseline (232.097 us; speedup 1.0000x reference)
//
#include <hip/hip_runtime.h>
#include <hip/hip_bf16.h>

#define B_ 8
#define S_ 1024
#define H_ 1024
#define NH 16
#define DH 64
#define BS (B_*S_)
#define L2E 1.44269504f

typedef unsigned short u16;
typedef __attribute__((ext_vector_type(8))) short bf16x8;
typedef __attribute__((ext_vector_type(4))) float f32x4;
typedef __attribute__((ext_vector_type(16))) float f32x16;
typedef __attribute__((ext_vector_type(4))) u16 u16x4;
typedef __attribute__((ext_vector_type(2))) unsigned int u32x2;

#define MFMA(a,b,c)   __builtin_amdgcn_mfma_f32_16x16x32_bf16((a),(b),(c),0,0,0)
#define MFMA32(a,b,c) __builtin_amdgcn_mfma_f32_32x32x16_bf16((a),(b),(c),0,0,0)

__device__ __forceinline__ u16 f2bf(float f) {
  union { float f; unsigned u; } v; v.f = f;
  unsigned r = v.u + 0x7fffu + ((v.u >> 16) & 1u);
  return (u16)(r >> 16);
}

__device__ __forceinline__ unsigned packbf2(float a, float b) {
  union { __hip_bfloat162 h; unsigned u; } v;
  v.h = __float22bfloat162_rn(float2{a, b});
  return v.u;
}

__device__ __forceinline__ void gload16(const u16* g, u16* l) {
  __builtin_amdgcn_global_load_lds(
      (const __attribute__((address_space(1))) unsigned int*)g,
      (__attribute__((address_space(3))) unsigned int*)l, 16, 0, 0);
}

// ---------------- dcoef (+ fused weight f32->bf16 conversion)
__global__ __launch_bounds__(256) void dcoef_kernel(
    const float* __restrict__ qw, const float* __restrict__ kw,
    const float* __restrict__ vw, const float* __restrict__ ww,
    const float* __restrict__ uw, const float* __restrict__ styles,
    float* __restrict__ dc, u16* __restrict__ w16) {
  int bi = blockIdx.x;            // 5*1024
  int wsel = bi >> 10;
  int o = bi & 1023;
  const float* W = (wsel == 0) ? qw : (wsel == 1) ? kw : (wsel == 2) ? vw
                   : (wsel == 3) ? ww : uw;
  int soff = (wsel < 3) ? 0 : H_;
  int tid = threadIdx.x;
  float4 w4 = *(const float4*)(W + (size_t)o * H_ + tid * 4);
  u16x4 wo = { f2bf(w4.x), f2bf(w4.y), f2bf(w4.z), f2bf(w4.w) };
  *(u16x4*)(w16 + (size_t)wsel * H_ * H_ + (size_t)o * H_ + tid * 4) = wo;
  float w2x = w4.x * w4.x, w2y = w4.y * w4.y, w2z = w4.z * w4.z, w2w = w4.w * w4.w;
  float acc[8];
#pragma unroll
  for (int b = 0; b < 8; b++) {
    float4 s4 = *(const float4*)(styles + (size_t)b * 2 * H_ + soff + tid * 4);
    acc[b] = w2x * s4.x * s4.x + w2y * s4.y * s4.y + w2z * s4.z * s4.z + w2w * s4.w * s4.w;
  }
#pragma unroll
  for (int off = 1; off < 64; off <<= 1)
#pragma unroll
    for (int b = 0; b < 8; b++) acc[b] += __shfl_xor(acc[b], off);
  __shared__ float red[4][8];
  int w = tid >> 6, l = tid & 63;
  if (l == 0)
#pragma unroll
    for (int b = 0; b < 8; b++) red[w][b] = acc[b];
  __syncthreads();
  if (tid < 8) {
    int b = tid;
    float v = red[0][b] + red[1][b] + red[2][b] + red[3][b];
    float r = rsqrtf(v + 1e-8f);
    if (wsel == 2) r *= styles[(size_t)b * 2 * H_ + H_ + o];
    dc[(size_t)wsel * B_ * H_ + b * H_ + o] = r;
  }
}

// ---------------- style-scale + layernorm, bf16 out
__global__ __launch_bounds__(256) void ln_kernel(
    const float* __restrict__ x, const float* __restrict__ styles,
    u16* __restrict__ xn) {
  int row = blockIdx.x;        // 8192
  int b = row >> 10;
  int tid = threadIdx.x;
  const float4 xv = *(const float4*)(x + (size_t)row * H_ + tid * 4);
  const float4 sv = *(const float4*)(styles + (size_t)b * 2 * H_ + tid * 4);
  float v0 = xv.x * sv.x, v1 = xv.y * sv.y, v2 = xv.z * sv.z, v3 = xv.w * sv.w;
  float sum = v0 + v1 + v2 + v3;
  float sq = v0 * v0 + v1 * v1 + v2 * v2 + v3 * v3;
#pragma unroll
  for (int off = 1; off < 64; off <<= 1) {
    sum += __shfl_xor(sum, off);
    sq += __shfl_xor(sq, off);
  }
  __shared__ float rsum[4], rsq[4];
  int w = tid >> 6;
  if ((tid & 63) == 0) { rsum[w] = sum; rsq[w] = sq; }
  __syncthreads();
  sum = rsum[0] + rsum[1] + rsum[2] + rsum[3];
  sq = rsq[0] + rsq[1] + rsq[2] + rsq[3];
  float mean = sum * (1.f / H_);
  float var = sq * (1.f / H_) - mean * mean;
  float rstd = rsqrtf(var + 1e-5f);
  u16x4 o = { f2bf((v0 - mean) * rstd), f2bf((v1 - mean) * rstd),
              f2bf((v2 - mean) * rstd), f2bf((v3 - mean) * rstd) };
  *(u16x4*)(xn + (size_t)row * H_ + tid * 4) = o;
}

// ---------------- 128x128 NT GEMM core (m97-style, measured-best: R8 73.5us)
__device__ __forceinline__ void gemm128_core(
    const u16* __restrict__ Arow, const u16* __restrict__ Brow, int K,
    u16* ldsA, u16* ldsB, f32x4 acc[4][4]) {
  const int tid = threadIdx.x;
  const int l = tid & 63, w = tid >> 6;
  const int wm = (w >> 1) * 64, wn = (w & 1) * 64;
  const int lrow = l & 15, lko = (l >> 4) * 8;
  const int srow = tid >> 2;
  const int scol = (tid & 3) * 8;
  for (int k0 = 0; k0 < K; k0 += 32) {
    __syncthreads();
    gload16(Arow + (size_t)srow * K + k0 + scol,        ldsA + srow * 32 + scol);
    gload16(Arow + (size_t)(srow + 64) * K + k0 + scol, ldsA + (srow + 64) * 32 + scol);
    gload16(Brow + (size_t)srow * K + k0 + scol,        ldsB + srow * 32 + scol);
    gload16(Brow + (size_t)(srow + 64) * K + k0 + scol, ldsB + (srow + 64) * 32 + scol);
    __syncthreads();
    bf16x8 af[4], bfr[4];
#pragma unroll
    for (int i = 0; i < 4; i++)
      af[i] = *(const bf16x8*)&ldsA[(wm + i * 16 + lrow) * 32 + lko];
#pragma unroll
    for (int i = 0; i < 4; i++)
      bfr[i] = *(const bf16x8*)&ldsB[(wn + i * 16 + lrow) * 32 + lko];
#pragma unroll
    for (int mi = 0; mi < 4; mi++)
#pragma unroll
      for (int ni = 0; ni < 4; ni++)
        acc[mi][ni] = MFMA(af[mi], bfr[ni], acc[mi][ni]);
  }
}

// ---------------- QKV GEMM: xn[8192,1024] @ w16[0..3072][1024]^T
// Grid 1536 1D; XCD r owns bn in {3r..3r+2} (weight panels L2-resident).
__global__ __launch_bounds__(256) void qkv_kernel(
    const u16* __restrict__ xn, const u16* __restrict__ w16,
    const float* __restrict__ dc, u16* __restrict__ Qb, u16* __restrict__ Kb,
    u16* __restrict__ VT, u16* __restrict__ vfl) {
  __shared__ u16 ldsA[128 * 32], ldsB[128 * 32];
  int bid = blockIdx.x;
  int r = bid & 7, idx = bid >> 3;       // idx 0..191
  int bm = idx & 63;                     // 64
  int bn = r * 3 + (idx >> 6);           // 24
  f32x4 acc[4][4] = {};
  gemm128_core(xn + (size_t)bm * 128 * H_, w16 + (size_t)bn * 128 * H_, H_,
               ldsA, ldsB, acc);
  int l = threadIdx.x & 63, w = threadIdx.x >> 6;
  int wm = (w >> 1) * 64, wn = (w & 1) * 64;
  int wsel = bn >> 3;
  int col0 = (bn & 7) * 128 + wn;
  int row0 = bm * 128 + wm;
  const float* dcw = dc + (size_t)wsel * B_ * H_;
  // fold 1/sqrt(d) and log2(e) into Q so attention can use raw exp2
  float extra = (wsel == 0) ? 0.125f * L2E : 1.0f;
#pragma unroll
  for (int mi = 0; mi < 4; mi++) {
#pragma unroll
    for (int ni = 0; ni < 4; ni++) {
      int col = col0 + ni * 16 + (l & 15);
      int hh = col >> 6, dd = col & 63;
      int s_base = (row0 + mi * 16 + (l >> 4) * 4) & 1023;
      int b = (row0 + mi * 16 + (l >> 4) * 4) >> 10;
      float dcv = dcw[b * H_ + col] * extra;
      u16 bv[4];
#pragma unroll
      for (int rr = 0; rr < 4; rr++)
        bv[rr] = f2bf(acc[mi][ni][rr] * dcv);
      if (wsel == 0) {
#pragma unroll
        for (int rr = 0; rr < 4; rr++)
          Qb[((size_t)(b * NH + hh) * S_ + s_base + rr) * DH + dd] = bv[rr];
      } else if (wsel == 1) {
#pragma unroll
        for (int rr = 0; rr < 4; rr++)
          Kb[((size_t)(b * NH + hh) * S_ + s_base + rr) * DH + dd] = bv[rr];
      } else {
        u16x4 pv = { bv[0], bv[1], bv[2], bv[3] };
        *(u16x4*)&VT[((size_t)(b * NH + hh) * DH + dd) * S_ + s_base] = pv;
#pragma unroll
        for (int rr = 0; rr < 4; rr++)
          vfl[(size_t)(row0 + mi * 16 + (l >> 4) * 4 + rr) * H_ + col] = bv[rr];
      }
    }
  }
}

// ---------------- flash attention (R8 version: 32 q-rows/wave, in-reg P)
__global__ __launch_bounds__(512) void attn_kernel(
    const u16* __restrict__ Qb, const u16* __restrict__ Kb,
    const u16* __restrict__ VT, u16* __restrict__ xat) {
  __shared__ u16 ldsK[3][64 * 64];
  __shared__ u16 ldsV[3][64 * 64];
  int tid = threadIdx.x;
  int l = tid & 63, w = tid >> 6;   // 8 waves, 32 q-rows each
  int id = blockIdx.x;
  int r = id & 7, rest = id >> 3;
  int qblk = rest & 3, a = rest >> 2;
  int hl = a * 8 + r;              // XCD-locality: same head -> same XCD
  int h = hl & 15, b = hl >> 4;
  int q0 = qblk * 256 + w * 32;
  const u16* Qp = Qb + ((size_t)(b * NH + h) * S_ + q0) * DH;
  const u16* Kp = Kb + (size_t)(b * NH + h) * S_ * DH;
  const u16* Vp = VT + (size_t)(b * NH + h) * DH * S_;
  int lq = l & 31, hi = l >> 5;
  int srow = tid >> 3, schunk = tid & 7;
  int ssw = (schunk * 8) ^ ((srow & 7) << 3);
  const u16* Ksrc = Kp + (size_t)srow * DH + ssw;
  const u16* Vsrc = Vp + (size_t)srow * S_ + ssw;
  int sdst = srow * 64 + schunk * 8;
  gload16(Ksrc, &ldsK[0][sdst]);
  gload16(Vsrc, &ldsV[0][sdst]);
  gload16(Ksrc + 64 * DH, &ldsK[1][sdst]);
  gload16(Vsrc + 64,      &ldsV[1][sdst]);
  bf16x8 qf[4];
#pragma unroll
  for (int s = 0; s < 4; s++)
    qf[s] = *(const bf16x8*)(Qp + lq * 64 + s * 16 + hi * 8);
  f32x16 acc0 = {}, acc1 = {};   // OUT^T d-blocks 0..31 / 32..63
  float ls = 0.f;
  asm volatile("s_waitcnt vmcnt(2)" ::: "memory");
  __builtin_amdgcn_s_barrier();
  int cur = 0;
  for (int t = 0; t < 16; ++t) {
    if (t + 2 < 16) {
      int nb = cur + 2; if (nb >= 3) nb -= 3;
      gload16(Ksrc + (size_t)(t + 2) * 64 * DH, &ldsK[nb][sdst]);
      gload16(Vsrc + (size_t)(t + 2) * 64,      &ldsV[nb][sdst]);
    }
    const u16* Kt = &ldsK[cur][0];
    const u16* Vt = &ldsV[cur][0];
    f32x16 z0 = {}, z1 = {};
    __builtin_amdgcn_s_setprio(1);
#pragma unroll
    for (int s = 0; s < 4; s++) {
      int ch = ((s * 2 + hi) ^ (lq & 7)) * 8;
      bf16x8 kf0 = *(const bf16x8*)&Kt[lq * 64 + ch];
      bf16x8 kf1 = *(const bf16x8*)&Kt[(32 + lq) * 64 + ch];
      z0 = MFMA32(kf0, qf[s], z0);
      z1 = MFMA32(kf1, qf[s], z1);
    }
    __builtin_amdgcn_s_setprio(0);
    float rs = 0.f;
#pragma unroll
    for (int i = 0; i < 16; i++) {
      z0[i] = __builtin_exp2f(z0[i]); rs += z0[i];
      z1[i] = __builtin_exp2f(z1[i]); rs += z1[i];
    }
    rs += __shfl_xor(rs, 32);
    ls += rs;
    bf16x8 pf[4];
#pragma unroll
    for (int g = 0; g < 2; g++) {
      unsigned pa = packbf2(z0[g * 8 + 0], z0[g * 8 + 1]);
      unsigned pb = packbf2(z0[g * 8 + 2], z0[g * 8 + 3]);
      unsigned pc = packbf2(z0[g * 8 + 4], z0[g * 8 + 5]);
      unsigned pd = packbf2(z0[g * 8 + 6], z0[g * 8 + 7]);
      u32x2 sA = __builtin_amdgcn_permlane32_swap(pa, pc, false, false);
      u32x2 sB = __builtin_amdgcn_permlane32_swap(pb, pd, false, false);
      union { unsigned u[4]; bf16x8 v; } uu;
      uu.u[0] = sA[0]; uu.u[1] = sB[0]; uu.u[2] = sA[1]; uu.u[3] = sB[1];
      pf[g] = uu.v;
    }
#pragma unroll
    for (int g = 0; g < 2; g++) {
      unsigned pa = packbf2(z1[g * 8 + 0], z1[g * 8 + 1]);
      unsigned pb = packbf2(z1[g * 8 + 2], z1[g * 8 + 3]);
      unsigned pc = packbf2(z1[g * 8 + 4], z1[g * 8 + 5]);
      unsigned pd = packbf2(z1[g * 8 + 6], z1[g * 8 + 7]);
      u32x2 sA = __builtin_amdgcn_permlane32_swap(pa, pc, false, false);
      u32x2 sB = __builtin_amdgcn_permlane32_swap(pb, pd, false, false);
      union { unsigned u[4]; bf16x8 v; } uu;
      uu.u[0] = sA[0]; uu.u[1] = sB[0]; uu.u[2] = sA[1]; uu.u[3] = sB[1];
      pf[2 + g] = uu.v;
    }
    __builtin_amdgcn_s_setprio(1);
#pragma unroll
    for (int ks = 0; ks < 4; ks++) {
      int ch = ((ks * 2 + hi) ^ (lq & 7)) * 8;
      bf16x8 vf0 = *(const bf16x8*)&Vt[lq * 64 + ch];
      bf16x8 vf1 = *(const bf16x8*)&Vt[(32 + lq) * 64 + ch];
      acc0 = MFMA32(vf0, pf[ks], acc0);
      acc1 = MFMA32(vf1, pf[ks], acc1);
    }
    __builtin_amdgcn_s_setprio(0);
    if (t < 14) {
      asm volatile("s_waitcnt vmcnt(2)" ::: "memory");
    } else if (t == 14) {
      asm volatile("s_waitcnt vmcnt(0)" ::: "memory");
    }
    if (t < 15) __builtin_amdgcn_s_barrier();
    cur = (cur == 2) ? 0 : cur + 1;
  }
  float inv = 1.f / ls;
  size_t orow = ((size_t)b * S_ + q0 + lq) * H_ + h * DH;
#pragma unroll
  for (int g = 0; g < 4; g++) {
    int d0 = g * 8 + hi * 4;
    u16x4 o0 = { f2bf(acc0[g * 4 + 0] * inv), f2bf(acc0[g * 4 + 1] * inv),
                 f2bf(acc0[g * 4 + 2] * inv), f2bf(acc0[g * 4 + 3] * inv) };
    *(u16x4*)(xat + orow + d0) = o0;
    u16x4 o1 = { f2bf(acc1[g * 4 + 0] * inv), f2bf(acc1[g * 4 + 1] * inv),
                 f2bf(acc1[g * 4 + 2] * inv), f2bf(acc1[g * 4 + 3] * inv) };
    *(u16x4*)(xat + orow + 32 + d0) = o1;
  }
}

// ---------------- out GEMM: (xat@W^T)*wdc + (vfl@U^T)*udc, f32 out (R8)
// Grid 512 1D; XCD r owns bn=r exactly (one weight panel per XCD).
__global__ __launch_bounds__(256) void out_kernel(
    const u16* __restrict__ xat, const u16* __restrict__ vfl,
    const u16* __restrict__ w16, const float* __restrict__ dc,
    float* __restrict__ out) {
  __shared__ u16 ldsA[128 * 32], ldsB[128 * 32];
  int bid = blockIdx.x;
  int bn = bid & 7;                // 8 panels -> 8 XCDs
  int bm = bid >> 3;               // 64
  f32x4 acc[4][4] = {};
  gemm128_core(xat + (size_t)bm * 128 * H_,
               w16 + (size_t)3 * H_ * H_ + (size_t)bn * 128 * H_, H_,
               ldsA, ldsB, acc);
  int l = threadIdx.x & 63, w = threadIdx.x >> 6;
  int wm = (w >> 1) * 64, wn = (w & 1) * 64;
  int col0 = bn * 128 + wn;
  int row0 = bm * 128 + wm;
  int b = row0 >> 10;
  const float* wdc = dc + (size_t)3 * B_ * H_ + b * H_;
  const float* udc = dc + (size_t)4 * B_ * H_ + b * H_;
  float ratio[4], ud[4];
#pragma unroll
  for (int ni = 0; ni < 4; ni++) {
    int col = col0 + ni * 16 + (l & 15);
    ud[ni] = udc[col];
    ratio[ni] = wdc[col] / ud[ni];
  }
#pragma unroll
  for (int mi = 0; mi < 4; mi++)
#pragma unroll
    for (int ni = 0; ni < 4; ni++)
#pragma unroll
      for (int rr = 0; rr < 4; rr++) acc[mi][ni][rr] *= ratio[ni];
  gemm128_core(vfl + (size_t)bm * 128 * H_,
               w16 + (size_t)4 * H_ * H_ + (size_t)bn * 128 * H_, H_,
               ldsA, ldsB, acc);
#pragma unroll
  for (int mi = 0; mi < 4; mi++)
#pragma unroll
    for (int ni = 0; ni < 4; ni++) {
      int col = col0 + ni * 16 + (l & 15);
#pragma unroll
      for (int rr = 0; rr < 4; rr++) {
        int row = row0 + mi * 16 + (l >> 4) * 4 + rr;
        out[(size_t)row * H_ + col] = acc[mi][ni][rr] * ud[ni];
      }
    }
}

extern "C" void kernel_launch(void* const* d_in, const int* in_sizes, int n_in,
                              void* d_out, int out_size, void* d_ws, size_t ws_size,
                              hipStream_t stream) {
  const float* x = (const float*)d_in[0];
  const float* qw = (const float*)d_in[1];
  const float* kw = (const float*)d_in[2];
  const float* vw = (const float*)d_in[3];
  const float* ww = (const float*)d_in[4];
  const float* uw = (const float*)d_in[5];
  const float* styles = (const float*)d_in[6];
  float* out = (float*)d_out;

  char* ws = (char*)d_ws;
  size_t need = 163840 + (size_t)5 * H_ * H_ * 2 + (size_t)6 * BS * H_ * 2;
  if (ws_size < need) return;
  float* dc = (float*)ws;
  u16* w16 = (u16*)(ws + 163840);
  u16* xn  = w16 + (size_t)5 * H_ * H_;
  u16* Qb  = xn + (size_t)BS * H_;
  u16* Kb  = Qb + (size_t)BS * H_;
  u16* VT  = Kb + (size_t)BS * H_;
  u16* vfl = VT + (size_t)BS * H_;
  u16* xat = vfl + (size_t)BS * H_;

  dcoef_kernel<<<dim3(5 * H_), dim3(256), 0, stream>>>(qw, kw, vw, ww, uw, styles, dc, w16);
  ln_kernel<<<dim3(BS), dim3(256), 0, stream>>>(x, styles, xn);
  qkv_kernel<<<dim3(1536), dim3(256), 0, stream>>>(xn, w16, dc, Qb, Kb, VT, vfl);
  attn_kernel<<<dim3(512), dim3(512), 0, stream>>>(Qb, Kb, VT, xat);
  out_kernel<<<dim3(512), dim3(256), 0, stream>>>(xat, vfl, w16, dc, out);
}

// Round 15
// 204.988 us; speedup vs baseline: 1.1322x; 1.1322x over previous
//
#include <hip/hip_runtime.h>
#include <hip/hip_bf16.h>

#define B_ 8
#define S_ 1024
#define H_ 1024
#define NH 16
#define DH 64
#define BS (B_*S_)
#define L2E 1.44269504f

typedef unsigned short u16;
typedef __attribute__((ext_vector_type(8))) short bf16x8;
typedef __attribute__((ext_vector_type(4))) float f32x4;
typedef __attribute__((ext_vector_type(16))) float f32x16;
typedef __attribute__((ext_vector_type(4))) u16 u16x4;
typedef __attribute__((ext_vector_type(2))) unsigned int u32x2;

#define MFMA(a,b,c)   __builtin_amdgcn_mfma_f32_16x16x32_bf16((a),(b),(c),0,0,0)
#define MFMA32(a,b,c) __builtin_amdgcn_mfma_f32_32x32x16_bf16((a),(b),(c),0,0,0)

__device__ __forceinline__ u16 f2bf(float f) {
  union { float f; unsigned u; } v; v.f = f;
  unsigned r = v.u + 0x7fffu + ((v.u >> 16) & 1u);
  return (u16)(r >> 16);
}

__device__ __forceinline__ unsigned packbf2(float a, float b) {
  union { __hip_bfloat162 h; unsigned u; } v;
  v.h = __float22bfloat162_rn(float2{a, b});
  return v.u;
}

__device__ __forceinline__ void gload16(const u16* g, u16* l) {
  __builtin_amdgcn_global_load_lds(
      (const __attribute__((address_space(1))) unsigned int*)g,
      (__attribute__((address_space(3))) unsigned int*)l, 16, 0, 0);
}

// ---------------- dcoef (+ fused weight f32->bf16 conversion)
__global__ __launch_bounds__(256) void dcoef_kernel(
    const float* __restrict__ qw, const float* __restrict__ kw,
    const float* __restrict__ vw, const float* __restrict__ ww,
    const float* __restrict__ uw, const float* __restrict__ styles,
    float* __restrict__ dc, u16* __restrict__ w16) {
  int bi = blockIdx.x;            // 5*1024
  int wsel = bi >> 10;
  int o = bi & 1023;
  const float* W = (wsel == 0) ? qw : (wsel == 1) ? kw : (wsel == 2) ? vw
                   : (wsel == 3) ? ww : uw;
  int soff = (wsel < 3) ? 0 : H_;
  int tid = threadIdx.x;
  float4 w4 = *(const float4*)(W + (size_t)o * H_ + tid * 4);
  u16x4 wo = { f2bf(w4.x), f2bf(w4.y), f2bf(w4.z), f2bf(w4.w) };
  *(u16x4*)(w16 + (size_t)wsel * H_ * H_ + (size_t)o * H_ + tid * 4) = wo;
  float w2x = w4.x * w4.x, w2y = w4.y * w4.y, w2z = w4.z * w4.z, w2w = w4.w * w4.w;
  float acc[8];
#pragma unroll
  for (int b = 0; b < 8; b++) {
    float4 s4 = *(const float4*)(styles + (size_t)b * 2 * H_ + soff + tid * 4);
    acc[b] = w2x * s4.x * s4.x + w2y * s4.y * s4.y + w2z * s4.z * s4.z + w2w * s4.w * s4.w;
  }
#pragma unroll
  for (int off = 1; off < 64; off <<= 1)
#pragma unroll
    for (int b = 0; b < 8; b++) acc[b] += __shfl_xor(acc[b], off);
  __shared__ float red[4][8];
  int w = tid >> 6, l = tid & 63;
  if (l == 0)
#pragma unroll
    for (int b = 0; b < 8; b++) red[w][b] = acc[b];
  __syncthreads();
  if (tid < 8) {
    int b = tid;
    float v = red[0][b] + red[1][b] + red[2][b] + red[3][b];
    float r = rsqrtf(v + 1e-8f);
    if (wsel == 2) r *= styles[(size_t)b * 2 * H_ + H_ + o];
    dc[(size_t)wsel * B_ * H_ + b * H_ + o] = r;
  }
}

// ---------------- style-scale + layernorm, bf16 out
__global__ __launch_bounds__(256) void ln_kernel(
    const float* __restrict__ x, const float* __restrict__ styles,
    u16* __restrict__ xn) {
  int row = blockIdx.x;        // 8192
  int b = row >> 10;
  int tid = threadIdx.x;
  const float4 xv = *(const float4*)(x + (size_t)row * H_ + tid * 4);
  const float4 sv = *(const float4*)(styles + (size_t)b * 2 * H_ + tid * 4);
  float v0 = xv.x * sv.x, v1 = xv.y * sv.y, v2 = xv.z * sv.z, v3 = xv.w * sv.w;
  float sum = v0 + v1 + v2 + v3;
  float sq = v0 * v0 + v1 * v1 + v2 * v2 + v3 * v3;
#pragma unroll
  for (int off = 1; off < 64; off <<= 1) {
    sum += __shfl_xor(sum, off);
    sq += __shfl_xor(sq, off);
  }
  __shared__ float rsum[4], rsq[4];
  int w = tid >> 6;
  if ((tid & 63) == 0) { rsum[w] = sum; rsq[w] = sq; }
  __syncthreads();
  sum = rsum[0] + rsum[1] + rsum[2] + rsum[3];
  sq = rsq[0] + rsq[1] + rsq[2] + rsq[3];
  float mean = sum * (1.f / H_);
  float var = sq * (1.f / H_) - mean * mean;
  float rstd = rsqrtf(var + 1e-5f);
  u16x4 o = { f2bf((v0 - mean) * rstd), f2bf((v1 - mean) * rstd),
              f2bf((v2 - mean) * rstd), f2bf((v3 - mean) * rstd) };
  *(u16x4*)(xn + (size_t)row * H_ + tid * 4) = o;
}

// ---------------- 128x128 NT GEMM core (m97-style, measured-best: R8 73.5us)
__device__ __forceinline__ void gemm128_core(
    const u16* __restrict__ Arow, const u16* __restrict__ Brow, int K,
    u16* ldsA, u16* ldsB, f32x4 acc[4][4]) {
  const int tid = threadIdx.x;
  const int l = tid & 63, w = tid >> 6;
  const int wm = (w >> 1) * 64, wn = (w & 1) * 64;
  const int lrow = l & 15, lko = (l >> 4) * 8;
  const int srow = tid >> 2;
  const int scol = (tid & 3) * 8;
  for (int k0 = 0; k0 < K; k0 += 32) {
    __syncthreads();
    gload16(Arow + (size_t)srow * K + k0 + scol,        ldsA + srow * 32 + scol);
    gload16(Arow + (size_t)(srow + 64) * K + k0 + scol, ldsA + (srow + 64) * 32 + scol);
    gload16(Brow + (size_t)srow * K + k0 + scol,        ldsB + srow * 32 + scol);
    gload16(Brow + (size_t)(srow + 64) * K + k0 + scol, ldsB + (srow + 64) * 32 + scol);
    __syncthreads();
    bf16x8 af[4], bfr[4];
#pragma unroll
    for (int i = 0; i < 4; i++)
      af[i] = *(const bf16x8*)&ldsA[(wm + i * 16 + lrow) * 32 + lko];
#pragma unroll
    for (int i = 0; i < 4; i++)
      bfr[i] = *(const bf16x8*)&ldsB[(wn + i * 16 + lrow) * 32 + lko];
#pragma unroll
    for (int mi = 0; mi < 4; mi++)
#pragma unroll
      for (int ni = 0; ni < 4; ni++)
        acc[mi][ni] = MFMA(af[mi], bfr[ni], acc[mi][ni]);
  }
}

// ---------------- QKV GEMM, operand-swapped: A-frag = weights (rows = o),
// B-frag = xn (rows = s). C: col(lane&15)=s, row(rr)=o contiguous -> Q/K/vfl
// stores vectorize to u16x4 along o. Core/staging byte-identical to R8.
__global__ __launch_bounds__(256) void qkv_kernel(
    const u16* __restrict__ xn, const u16* __restrict__ w16,
    const float* __restrict__ dc, u16* __restrict__ Qb, u16* __restrict__ Kb,
    u16* __restrict__ VT, u16* __restrict__ vfl) {
  __shared__ u16 ldsA[128 * 32], ldsB[128 * 32];
  int bm = blockIdx.x;   // 64  (s-panels)
  int bn = blockIdx.y;   // 24  (o-panels)
  f32x4 acc[4][4] = {};
  gemm128_core(w16 + (size_t)bn * 128 * H_, xn + (size_t)bm * 128 * H_, H_,
               ldsA, ldsB, acc);
  int l = threadIdx.x & 63, w = threadIdx.x >> 6;
  int wm = (w >> 1) * 64, wn = (w & 1) * 64;
  int lr = l & 15, lg = l >> 4;
  int wsel = bn >> 3;
  int o_base = (bn & 7) * 128 + wm;      // col within output matrix (o)
  int s_row0 = bm * 128 + wn;            // s rows
  int b = s_row0 >> 10;                  // constant per block (128 | 1024)
  const float* dcw = dc + (size_t)wsel * B_ * H_ + (size_t)b * H_;
  float extra = (wsel == 0) ? 0.125f * L2E : 1.0f;
#pragma unroll
  for (int mi = 0; mi < 4; mi++) {
    int o0 = o_base + mi * 16 + lg * 4;  // 4-aligned, rr contiguous
    int hh = o0 >> 6, dd0 = o0 & 63;
    float dcv[4];
#pragma unroll
    for (int rr = 0; rr < 4; rr++) dcv[rr] = dcw[o0 + rr] * extra;
#pragma unroll
    for (int ni = 0; ni < 4; ni++) {
      int s = s_row0 + ni * 16 + lr;
      int sloc = s & 1023;
      u16x4 bv = { f2bf(acc[mi][ni][0] * dcv[0]), f2bf(acc[mi][ni][1] * dcv[1]),
                   f2bf(acc[mi][ni][2] * dcv[2]), f2bf(acc[mi][ni][3] * dcv[3]) };
      if (wsel == 0) {
        *(u16x4*)&Qb[((size_t)(b * NH + hh) * S_ + sloc) * DH + dd0] = bv;
      } else if (wsel == 1) {
        *(u16x4*)&Kb[((size_t)(b * NH + hh) * S_ + sloc) * DH + dd0] = bv;
      } else {
        *(u16x4*)&vfl[(size_t)s * H_ + o0] = bv;
#pragma unroll
        for (int rr = 0; rr < 4; rr++)
          VT[((size_t)(b * NH + hh) * DH + dd0 + rr) * S_ + sloc] = bv[rr];
      }
    }
  }
}

// ---------------- flash attention (R8 version: 32 q-rows/wave, in-reg P)
__global__ __launch_bounds__(512) void attn_kernel(
    const u16* __restrict__ Qb, const u16* __restrict__ Kb,
    const u16* __restrict__ VT, u16* __restrict__ xat) {
  __shared__ u16 ldsK[3][64 * 64];
  __shared__ u16 ldsV[3][64 * 64];
  int tid = threadIdx.x;
  int l = tid & 63, w = tid >> 6;   // 8 waves, 32 q-rows each
  int id = blockIdx.x;
  int r = id & 7, rest = id >> 3;
  int qblk = rest & 3, a = rest >> 2;
  int hl = a * 8 + r;              // XCD-locality: same head -> same XCD
  int h = hl & 15, b = hl >> 4;
  int q0 = qblk * 256 + w * 32;
  const u16* Qp = Qb + ((size_t)(b * NH + h) * S_ + q0) * DH;
  const u16* Kp = Kb + (size_t)(b * NH + h) * S_ * DH;
  const u16* Vp = VT + (size_t)(b * NH + h) * DH * S_;
  int lq = l & 31, hi = l >> 5;
  int srow = tid >> 3, schunk = tid & 7;
  int ssw = (schunk * 8) ^ ((srow & 7) << 3);
  const u16* Ksrc = Kp + (size_t)srow * DH + ssw;
  const u16* Vsrc = Vp + (size_t)srow * S_ + ssw;
  int sdst = srow * 64 + schunk * 8;
  gload16(Ksrc, &ldsK[0][sdst]);
  gload16(Vsrc, &ldsV[0][sdst]);
  gload16(Ksrc + 64 * DH, &ldsK[1][sdst]);
  gload16(Vsrc + 64,      &ldsV[1][sdst]);
  bf16x8 qf[4];
#pragma unroll
  for (int s = 0; s < 4; s++)
    qf[s] = *(const bf16x8*)(Qp + lq * 64 + s * 16 + hi * 8);
  f32x16 acc0 = {}, acc1 = {};   // OUT^T d-blocks 0..31 / 32..63
  float ls = 0.f;
  asm volatile("s_waitcnt vmcnt(2)" ::: "memory");
  __builtin_amdgcn_s_barrier();
  int cur = 0;
  for (int t = 0; t < 16; ++t) {
    if (t + 2 < 16) {
      int nb = cur + 2; if (nb >= 3) nb -= 3;
      gload16(Ksrc + (size_t)(t + 2) * 64 * DH, &ldsK[nb][sdst]);
      gload16(Vsrc + (size_t)(t + 2) * 64,      &ldsV[nb][sdst]);
    }
    const u16* Kt = &ldsK[cur][0];
    const u16* Vt = &ldsV[cur][0];
    f32x16 z0 = {}, z1 = {};
    __builtin_amdgcn_s_setprio(1);
#pragma unroll
    for (int s = 0; s < 4; s++) {
      int ch = ((s * 2 + hi) ^ (lq & 7)) * 8;
      bf16x8 kf0 = *(const bf16x8*)&Kt[lq * 64 + ch];
      bf16x8 kf1 = *(const bf16x8*)&Kt[(32 + lq) * 64 + ch];
      z0 = MFMA32(kf0, qf[s], z0);
      z1 = MFMA32(kf1, qf[s], z1);
    }
    __builtin_amdgcn_s_setprio(0);
    float rs = 0.f;
#pragma unroll
    for (int i = 0; i < 16; i++) {
      z0[i] = __builtin_exp2f(z0[i]); rs += z0[i];
      z1[i] = __builtin_exp2f(z1[i]); rs += z1[i];
    }
    rs += __shfl_xor(rs, 32);
    ls += rs;
    bf16x8 pf[4];
#pragma unroll
    for (int g = 0; g < 2; g++) {
      unsigned pa = packbf2(z0[g * 8 + 0], z0[g * 8 + 1]);
      unsigned pb = packbf2(z0[g * 8 + 2], z0[g * 8 + 3]);
      unsigned pc = packbf2(z0[g * 8 + 4], z0[g * 8 + 5]);
      unsigned pd = packbf2(z0[g * 8 + 6], z0[g * 8 + 7]);
      u32x2 sA = __builtin_amdgcn_permlane32_swap(pa, pc, false, false);
      u32x2 sB = __builtin_amdgcn_permlane32_swap(pb, pd, false, false);
      union { unsigned u[4]; bf16x8 v; } uu;
      uu.u[0] = sA[0]; uu.u[1] = sB[0]; uu.u[2] = sA[1]; uu.u[3] = sB[1];
      pf[g] = uu.v;
    }
#pragma unroll
    for (int g = 0; g < 2; g++) {
      unsigned pa = packbf2(z1[g * 8 + 0], z1[g * 8 + 1]);
      unsigned pb = packbf2(z1[g * 8 + 2], z1[g * 8 + 3]);
      unsigned pc = packbf2(z1[g * 8 + 4], z1[g * 8 + 5]);
      unsigned pd = packbf2(z1[g * 8 + 6], z1[g * 8 + 7]);
      u32x2 sA = __builtin_amdgcn_permlane32_swap(pa, pc, false, false);
      u32x2 sB = __builtin_amdgcn_permlane32_swap(pb, pd, false, false);
      union { unsigned u[4]; bf16x8 v; } uu;
      uu.u[0] = sA[0]; uu.u[1] = sB[0]; uu.u[2] = sA[1]; uu.u[3] = sB[1];
      pf[2 + g] = uu.v;
    }
    __builtin_amdgcn_s_setprio(1);
#pragma unroll
    for (int ks = 0; ks < 4; ks++) {
      int ch = ((ks * 2 + hi) ^ (lq & 7)) * 8;
      bf16x8 vf0 = *(const bf16x8*)&Vt[lq * 64 + ch];
      bf16x8 vf1 = *(const bf16x8*)&Vt[(32 + lq) * 64 + ch];
      acc0 = MFMA32(vf0, pf[ks], acc0);
      acc1 = MFMA32(vf1, pf[ks], acc1);
    }
    __builtin_amdgcn_s_setprio(0);
    if (t < 14) {
      asm volatile("s_waitcnt vmcnt(2)" ::: "memory");
    } else if (t == 14) {
      asm volatile("s_waitcnt vmcnt(0)" ::: "memory");
    }
    if (t < 15) __builtin_amdgcn_s_barrier();
    cur = (cur == 2) ? 0 : cur + 1;
  }
  float inv = 1.f / ls;
  size_t orow = ((size_t)b * S_ + q0 + lq) * H_ + h * DH;
#pragma unroll
  for (int g = 0; g < 4; g++) {
    int d0 = g * 8 + hi * 4;
    u16x4 o0 = { f2bf(acc0[g * 4 + 0] * inv), f2bf(acc0[g * 4 + 1] * inv),
                 f2bf(acc0[g * 4 + 2] * inv), f2bf(acc0[g * 4 + 3] * inv) };
    *(u16x4*)(xat + orow + d0) = o0;
    u16x4 o1 = { f2bf(acc1[g * 4 + 0] * inv), f2bf(acc1[g * 4 + 1] * inv),
                 f2bf(acc1[g * 4 + 2] * inv), f2bf(acc1[g * 4 + 3] * inv) };
    *(u16x4*)(xat + orow + 32 + d0) = o1;
  }
}

// ---------------- out GEMM, operand-swapped: rr runs along o -> float4 store.
__global__ __launch_bounds__(256) void out_kernel(
    const u16* __restrict__ xat, const u16* __restrict__ vfl,
    const u16* __restrict__ w16, const float* __restrict__ dc,
    float* __restrict__ out) {
  __shared__ u16 ldsA[128 * 32], ldsB[128 * 32];
  int bm = blockIdx.x;   // 64 (s-panels)
  int bn = blockIdx.y;   // 8  (o-panels)
  f32x4 accW[4][4] = {};
  gemm128_core(w16 + (size_t)3 * H_ * H_ + (size_t)bn * 128 * H_,
               xat + (size_t)bm * 128 * H_, H_, ldsA, ldsB, accW);
  int l = threadIdx.x & 63, w = threadIdx.x >> 6;
  int wm = (w >> 1) * 64, wn = (w & 1) * 64;
  int lr = l & 15, lg = l >> 4;
  int o_base = bn * 128 + wm;
  int s_row0 = bm * 128 + wn;
  int b = s_row0 >> 10;
  const float* wdc = dc + (size_t)3 * B_ * H_ + (size_t)b * H_;
  const float* udc = dc + (size_t)4 * B_ * H_ + (size_t)b * H_;
  float ratio[4][4], ud[4][4];
#pragma unroll
  for (int mi = 0; mi < 4; mi++) {
    int o0 = o_base + mi * 16 + lg * 4;
#pragma unroll
    for (int rr = 0; rr < 4; rr++) {
      ud[mi][rr] = udc[o0 + rr];
      ratio[mi][rr] = wdc[o0 + rr] / ud[mi][rr];
    }
  }
#pragma unroll
  for (int mi = 0; mi < 4; mi++)
#pragma unroll
    for (int ni = 0; ni < 4; ni++)
#pragma unroll
      for (int rr = 0; rr < 4; rr++) accW[mi][ni][rr] *= ratio[mi][rr];
  gemm128_core(w16 + (size_t)4 * H_ * H_ + (size_t)bn * 128 * H_,
               vfl + (size_t)bm * 128 * H_, H_, ldsA, ldsB, accW);
#pragma unroll
  for (int mi = 0; mi < 4; mi++) {
    int o0 = o_base + mi * 16 + lg * 4;
#pragma unroll
    for (int ni = 0; ni < 4; ni++) {
      int s = s_row0 + ni * 16 + lr;
      float4 ov = { accW[mi][ni][0] * ud[mi][0], accW[mi][ni][1] * ud[mi][1],
                    accW[mi][ni][2] * ud[mi][2], accW[mi][ni][3] * ud[mi][3] };
      *(float4*)&out[(size_t)s * H_ + o0] = ov;
    }
  }
}

extern "C" void kernel_launch(void* const* d_in, const int* in_sizes, int n_in,
                              void* d_out, int out_size, void* d_ws, size_t ws_size,
                              hipStream_t stream) {
  const float* x = (const float*)d_in[0];
  const float* qw = (const float*)d_in[1];
  const float* kw = (const float*)d_in[2];
  const float* vw = (const float*)d_in[3];
  const float* ww = (const float*)d_in[4];
  const float* uw = (const float*)d_in[5];
  const float* styles = (const float*)d_in[6];
  float* out = (float*)d_out;

  char* ws = (char*)d_ws;
  size_t need = 163840 + (size_t)5 * H_ * H_ * 2 + (size_t)6 * BS * H_ * 2;
  if (ws_size < need) return;
  float* dc = (float*)ws;
  u16* w16 = (u16*)(ws + 163840);
  u16* xn  = w16 + (size_t)5 * H_ * H_;
  u16* Qb  = xn + (size_t)BS * H_;
  u16* Kb  = Qb + (size_t)BS * H_;
  u16* VT  = Kb + (size_t)BS * H_;
  u16* vfl = VT + (size_t)BS * H_;
  u16* xat = vfl + (size_t)BS * H_;

  dcoef_kernel<<<dim3(5 * H_), dim3(256), 0, stream>>>(qw, kw, vw, ww, uw, styles, dc, w16);
  ln_kernel<<<dim3(BS), dim3(256), 0, stream>>>(x, styles, xn);
  qkv_kernel<<<dim3(64, 24), dim3(256), 0, stream>>>(xn, w16, dc, Qb, Kb, VT, vfl);
  attn_kernel<<<dim3(512), dim3(512), 0, stream>>>(Qb, Kb, VT, xat);
  out_kernel<<<dim3(64, 8), dim3(256), 0, stream>>>(xat, vfl, w16, dc, out);
}

// Round 16
// 199.333 us; speedup vs baseline: 1.1644x; 1.0284x over previous
//
#include <hip/hip_runtime.h>
#include <hip/hip_bf16.h>

#define B_ 8
#define S_ 1024
#define H_ 1024
#define NH 16
#define DH 64
#define BS (B_*S_)
#define L2E 1.44269504f

typedef unsigned short u16;
typedef __attribute__((ext_vector_type(8))) short bf16x8;
typedef __attribute__((ext_vector_type(4))) float f32x4;
typedef __attribute__((ext_vector_type(16))) float f32x16;
typedef __attribute__((ext_vector_type(4))) u16 u16x4;
typedef __attribute__((ext_vector_type(2))) unsigned int u32x2;

#define MFMA(a,b,c)   __builtin_amdgcn_mfma_f32_16x16x32_bf16((a),(b),(c),0,0,0)
#define MFMA32(a,b,c) __builtin_amdgcn_mfma_f32_32x32x16_bf16((a),(b),(c),0,0,0)

__device__ __forceinline__ u16 f2bf(float f) {
  union { float f; unsigned u; } v; v.f = f;
  unsigned r = v.u + 0x7fffu + ((v.u >> 16) & 1u);
  return (u16)(r >> 16);
}

__device__ __forceinline__ unsigned packbf2(float a, float b) {
  union { __hip_bfloat162 h; unsigned u; } v;
  v.h = __float22bfloat162_rn(float2{a, b});
  return v.u;
}

__device__ __forceinline__ void gload16(const u16* g, u16* l) {
  __builtin_amdgcn_global_load_lds(
      (const __attribute__((address_space(1))) unsigned int*)g,
      (__attribute__((address_space(3))) unsigned int*)l, 16, 0, 0);
}

// ---------------- fused prep: dcoef (+weight bf16 conversion) AND layernorm
// blocks [0,5120): dcoef for (wsel,o); blocks [5120,13312): ln row.
__global__ __launch_bounds__(256) void prep_kernel(
    const float* __restrict__ qw, const float* __restrict__ kw,
    const float* __restrict__ vw, const float* __restrict__ ww,
    const float* __restrict__ uw, const float* __restrict__ styles,
    const float* __restrict__ x,
    float* __restrict__ dc, u16* __restrict__ w16, u16* __restrict__ xn) {
  __shared__ float red[4][8];
  int tid = threadIdx.x;
  int blk = blockIdx.x;
  if (blk < 5120) {
    // ---- dcoef + wconv (R8 body) ----
    int wsel = blk >> 10;
    int o = blk & 1023;
    const float* W = (wsel == 0) ? qw : (wsel == 1) ? kw : (wsel == 2) ? vw
                     : (wsel == 3) ? ww : uw;
    int soff = (wsel < 3) ? 0 : H_;
    float4 w4 = *(const float4*)(W + (size_t)o * H_ + tid * 4);
    u16x4 wo = { f2bf(w4.x), f2bf(w4.y), f2bf(w4.z), f2bf(w4.w) };
    *(u16x4*)(w16 + (size_t)wsel * H_ * H_ + (size_t)o * H_ + tid * 4) = wo;
    float w2x = w4.x * w4.x, w2y = w4.y * w4.y, w2z = w4.z * w4.z, w2w = w4.w * w4.w;
    float acc[8];
#pragma unroll
    for (int b = 0; b < 8; b++) {
      float4 s4 = *(const float4*)(styles + (size_t)b * 2 * H_ + soff + tid * 4);
      acc[b] = w2x * s4.x * s4.x + w2y * s4.y * s4.y + w2z * s4.z * s4.z + w2w * s4.w * s4.w;
    }
#pragma unroll
    for (int off = 1; off < 64; off <<= 1)
#pragma unroll
      for (int b = 0; b < 8; b++) acc[b] += __shfl_xor(acc[b], off);
    int w = tid >> 6, l = tid & 63;
    if (l == 0)
#pragma unroll
      for (int b = 0; b < 8; b++) red[w][b] = acc[b];
    __syncthreads();
    if (tid < 8) {
      int b = tid;
      float v = red[0][b] + red[1][b] + red[2][b] + red[3][b];
      float r = rsqrtf(v + 1e-8f);
      if (wsel == 2) r *= styles[(size_t)b * 2 * H_ + H_ + o];
      dc[(size_t)wsel * B_ * H_ + b * H_ + o] = r;
    }
  } else {
    // ---- style-scale + layernorm (R8 body) ----
    int row = blk - 5120;        // 8192
    int b = row >> 10;
    const float4 xv = *(const float4*)(x + (size_t)row * H_ + tid * 4);
    const float4 sv = *(const float4*)(styles + (size_t)b * 2 * H_ + tid * 4);
    float v0 = xv.x * sv.x, v1 = xv.y * sv.y, v2 = xv.z * sv.z, v3 = xv.w * sv.w;
    float sum = v0 + v1 + v2 + v3;
    float sq = v0 * v0 + v1 * v1 + v2 * v2 + v3 * v3;
#pragma unroll
    for (int off = 1; off < 64; off <<= 1) {
      sum += __shfl_xor(sum, off);
      sq += __shfl_xor(sq, off);
    }
    int w = tid >> 6;
    if ((tid & 63) == 0) { red[0][w] = sum; red[1][w] = sq; }
    __syncthreads();
    sum = red[0][0] + red[0][1] + red[0][2] + red[0][3];
    sq = red[1][0] + red[1][1] + red[1][2] + red[1][3];
    float mean = sum * (1.f / H_);
    float var = sq * (1.f / H_) - mean * mean;
    float rstd = rsqrtf(var + 1e-5f);
    u16x4 o = { f2bf((v0 - mean) * rstd), f2bf((v1 - mean) * rstd),
                f2bf((v2 - mean) * rstd), f2bf((v3 - mean) * rstd) };
    *(u16x4*)(xn + (size_t)row * H_ + tid * 4) = o;
  }
}

// ---------------- 128x128 NT GEMM core (m97-style, measured-best: R8 73.5us)
__device__ __forceinline__ void gemm128_core(
    const u16* __restrict__ Arow, const u16* __restrict__ Brow, int K,
    u16* ldsA, u16* ldsB, f32x4 acc[4][4]) {
  const int tid = threadIdx.x;
  const int l = tid & 63, w = tid >> 6;
  const int wm = (w >> 1) * 64, wn = (w & 1) * 64;
  const int lrow = l & 15, lko = (l >> 4) * 8;
  const int srow = tid >> 2;
  const int scol = (tid & 3) * 8;
  for (int k0 = 0; k0 < K; k0 += 32) {
    __syncthreads();
    gload16(Arow + (size_t)srow * K + k0 + scol,        ldsA + srow * 32 + scol);
    gload16(Arow + (size_t)(srow + 64) * K + k0 + scol, ldsA + (srow + 64) * 32 + scol);
    gload16(Brow + (size_t)srow * K + k0 + scol,        ldsB + srow * 32 + scol);
    gload16(Brow + (size_t)(srow + 64) * K + k0 + scol, ldsB + (srow + 64) * 32 + scol);
    __syncthreads();
    bf16x8 af[4], bfr[4];
#pragma unroll
    for (int i = 0; i < 4; i++)
      af[i] = *(const bf16x8*)&ldsA[(wm + i * 16 + lrow) * 32 + lko];
#pragma unroll
    for (int i = 0; i < 4; i++)
      bfr[i] = *(const bf16x8*)&ldsB[(wn + i * 16 + lrow) * 32 + lko];
#pragma unroll
    for (int mi = 0; mi < 4; mi++)
#pragma unroll
      for (int ni = 0; ni < 4; ni++)
        acc[mi][ni] = MFMA(af[mi], bfr[ni], acc[mi][ni]);
  }
}

// ---------------- QKV GEMM: xn[8192,1024] @ w16[0..3072][1024]^T (R8 config)
__global__ __launch_bounds__(256) void qkv_kernel(
    const u16* __restrict__ xn, const u16* __restrict__ w16,
    const float* __restrict__ dc, u16* __restrict__ Qb, u16* __restrict__ Kb,
    u16* __restrict__ VT, u16* __restrict__ vfl) {
  __shared__ u16 ldsA[128 * 32], ldsB[128 * 32];
  int bm = blockIdx.x;   // 64
  int bn = blockIdx.y;   // 24
  f32x4 acc[4][4] = {};
  gemm128_core(xn + (size_t)bm * 128 * H_, w16 + (size_t)bn * 128 * H_, H_,
               ldsA, ldsB, acc);
  int l = threadIdx.x & 63, w = threadIdx.x >> 6;
  int wm = (w >> 1) * 64, wn = (w & 1) * 64;
  int wsel = bn >> 3;
  int col0 = (bn & 7) * 128 + wn;
  int row0 = bm * 128 + wm;
  const float* dcw = dc + (size_t)wsel * B_ * H_;
  // fold 1/sqrt(d) and log2(e) into Q so attention can use raw exp2
  float extra = (wsel == 0) ? 0.125f * L2E : 1.0f;
#pragma unroll
  for (int mi = 0; mi < 4; mi++) {
#pragma unroll
    for (int ni = 0; ni < 4; ni++) {
      int col = col0 + ni * 16 + (l & 15);
      int hh = col >> 6, dd = col & 63;
      int s_base = (row0 + mi * 16 + (l >> 4) * 4) & 1023;
      int b = (row0 + mi * 16 + (l >> 4) * 4) >> 10;
      float dcv = dcw[b * H_ + col] * extra;
      u16 bv[4];
#pragma unroll
      for (int rr = 0; rr < 4; rr++)
        bv[rr] = f2bf(acc[mi][ni][rr] * dcv);
      if (wsel == 0) {
#pragma unroll
        for (int rr = 0; rr < 4; rr++)
          Qb[((size_t)(b * NH + hh) * S_ + s_base + rr) * DH + dd] = bv[rr];
      } else if (wsel == 1) {
#pragma unroll
        for (int rr = 0; rr < 4; rr++)
          Kb[((size_t)(b * NH + hh) * S_ + s_base + rr) * DH + dd] = bv[rr];
      } else {
        u16x4 pv = { bv[0], bv[1], bv[2], bv[3] };
        *(u16x4*)&VT[((size_t)(b * NH + hh) * DH + dd) * S_ + s_base] = pv;
#pragma unroll
        for (int rr = 0; rr < 4; rr++)
          vfl[(size_t)(row0 + mi * 16 + (l >> 4) * 4 + rr) * H_ + col] = bv[rr];
      }
    }
  }
}

// ---------------- flash attention (R8 version: 32 q-rows/wave, in-reg P)
__global__ __launch_bounds__(512) void attn_kernel(
    const u16* __restrict__ Qb, const u16* __restrict__ Kb,
    const u16* __restrict__ VT, u16* __restrict__ xat) {
  __shared__ u16 ldsK[3][64 * 64];
  __shared__ u16 ldsV[3][64 * 64];
  int tid = threadIdx.x;
  int l = tid & 63, w = tid >> 6;   // 8 waves, 32 q-rows each
  int id = blockIdx.x;
  int r = id & 7, rest = id >> 3;
  int qblk = rest & 3, a = rest >> 2;
  int hl = a * 8 + r;              // XCD-locality: same head -> same XCD
  int h = hl & 15, b = hl >> 4;
  int q0 = qblk * 256 + w * 32;
  const u16* Qp = Qb + ((size_t)(b * NH + h) * S_ + q0) * DH;
  const u16* Kp = Kb + (size_t)(b * NH + h) * S_ * DH;
  const u16* Vp = VT + (size_t)(b * NH + h) * DH * S_;
  int lq = l & 31, hi = l >> 5;
  int srow = tid >> 3, schunk = tid & 7;
  int ssw = (schunk * 8) ^ ((srow & 7) << 3);
  const u16* Ksrc = Kp + (size_t)srow * DH + ssw;
  const u16* Vsrc = Vp + (size_t)srow * S_ + ssw;
  int sdst = srow * 64 + schunk * 8;
  gload16(Ksrc, &ldsK[0][sdst]);
  gload16(Vsrc, &ldsV[0][sdst]);
  gload16(Ksrc + 64 * DH, &ldsK[1][sdst]);
  gload16(Vsrc + 64,      &ldsV[1][sdst]);
  bf16x8 qf[4];
#pragma unroll
  for (int s = 0; s < 4; s++)
    qf[s] = *(const bf16x8*)(Qp + lq * 64 + s * 16 + hi * 8);
  f32x16 acc0 = {}, acc1 = {};   // OUT^T d-blocks 0..31 / 32..63
  float ls = 0.f;
  asm volatile("s_waitcnt vmcnt(2)" ::: "memory");
  __builtin_amdgcn_s_barrier();
  int cur = 0;
  for (int t = 0; t < 16; ++t) {
    if (t + 2 < 16) {
      int nb = cur + 2; if (nb >= 3) nb -= 3;
      gload16(Ksrc + (size_t)(t + 2) * 64 * DH, &ldsK[nb][sdst]);
      gload16(Vsrc + (size_t)(t + 2) * 64,      &ldsV[nb][sdst]);
    }
    const u16* Kt = &ldsK[cur][0];
    const u16* Vt = &ldsV[cur][0];
    f32x16 z0 = {}, z1 = {};
    __builtin_amdgcn_s_setprio(1);
#pragma unroll
    for (int s = 0; s < 4; s++) {
      int ch = ((s * 2 + hi) ^ (lq & 7)) * 8;
      bf16x8 kf0 = *(const bf16x8*)&Kt[lq * 64 + ch];
      bf16x8 kf1 = *(const bf16x8*)&Kt[(32 + lq) * 64 + ch];
      z0 = MFMA32(kf0, qf[s], z0);
      z1 = MFMA32(kf1, qf[s], z1);
    }
    __builtin_amdgcn_s_setprio(0);
    float rs = 0.f;
#pragma unroll
    for (int i = 0; i < 16; i++) {
      z0[i] = __builtin_exp2f(z0[i]); rs += z0[i];
      z1[i] = __builtin_exp2f(z1[i]); rs += z1[i];
    }
    rs += __shfl_xor(rs, 32);
    ls += rs;
    bf16x8 pf[4];
#pragma unroll
    for (int g = 0; g < 2; g++) {
      unsigned pa = packbf2(z0[g * 8 + 0], z0[g * 8 + 1]);
      unsigned pb = packbf2(z0[g * 8 + 2], z0[g * 8 + 3]);
      unsigned pc = packbf2(z0[g * 8 + 4], z0[g * 8 + 5]);
      unsigned pd = packbf2(z0[g * 8 + 6], z0[g * 8 + 7]);
      u32x2 sA = __builtin_amdgcn_permlane32_swap(pa, pc, false, false);
      u32x2 sB = __builtin_amdgcn_permlane32_swap(pb, pd, false, false);
      union { unsigned u[4]; bf16x8 v; } uu;
      uu.u[0] = sA[0]; uu.u[1] = sB[0]; uu.u[2] = sA[1]; uu.u[3] = sB[1];
      pf[g] = uu.v;
    }
#pragma unroll
    for (int g = 0; g < 2; g++) {
      unsigned pa = packbf2(z1[g * 8 + 0], z1[g * 8 + 1]);
      unsigned pb = packbf2(z1[g * 8 + 2], z1[g * 8 + 3]);
      unsigned pc = packbf2(z1[g * 8 + 4], z1[g * 8 + 5]);
      unsigned pd = packbf2(z1[g * 8 + 6], z1[g * 8 + 7]);
      u32x2 sA = __builtin_amdgcn_permlane32_swap(pa, pc, false, false);
      u32x2 sB = __builtin_amdgcn_permlane32_swap(pb, pd, false, false);
      union { unsigned u[4]; bf16x8 v; } uu;
      uu.u[0] = sA[0]; uu.u[1] = sB[0]; uu.u[2] = sA[1]; uu.u[3] = sB[1];
      pf[2 + g] = uu.v;
    }
    __builtin_amdgcn_s_setprio(1);
#pragma unroll
    for (int ks = 0; ks < 4; ks++) {
      int ch = ((ks * 2 + hi) ^ (lq & 7)) * 8;
      bf16x8 vf0 = *(const bf16x8*)&Vt[lq * 64 + ch];
      bf16x8 vf1 = *(const bf16x8*)&Vt[(32 + lq) * 64 + ch];
      acc0 = MFMA32(vf0, pf[ks], acc0);
      acc1 = MFMA32(vf1, pf[ks], acc1);
    }
    __builtin_amdgcn_s_setprio(0);
    if (t < 14) {
      asm volatile("s_waitcnt vmcnt(2)" ::: "memory");
    } else if (t == 14) {
      asm volatile("s_waitcnt vmcnt(0)" ::: "memory");
    }
    if (t < 15) __builtin_amdgcn_s_barrier();
    cur = (cur == 2) ? 0 : cur + 1;
  }
  float inv = 1.f / ls;
  size_t orow = ((size_t)b * S_ + q0 + lq) * H_ + h * DH;
#pragma unroll
  for (int g = 0; g < 4; g++) {
    int d0 = g * 8 + hi * 4;
    u16x4 o0 = { f2bf(acc0[g * 4 + 0] * inv), f2bf(acc0[g * 4 + 1] * inv),
                 f2bf(acc0[g * 4 + 2] * inv), f2bf(acc0[g * 4 + 3] * inv) };
    *(u16x4*)(xat + orow + d0) = o0;
    u16x4 o1 = { f2bf(acc1[g * 4 + 0] * inv), f2bf(acc1[g * 4 + 1] * inv),
                 f2bf(acc1[g * 4 + 2] * inv), f2bf(acc1[g * 4 + 3] * inv) };
    *(u16x4*)(xat + orow + 32 + d0) = o1;
  }
}

// ---------------- out GEMM: (xat@W^T)*wdc + (vfl@U^T)*udc, f32 out (R8)
__global__ __launch_bounds__(256) void out_kernel(
    const u16* __restrict__ xat, const u16* __restrict__ vfl,
    const u16* __restrict__ w16, const float* __restrict__ dc,
    float* __restrict__ out) {
  __shared__ u16 ldsA[128 * 32], ldsB[128 * 32];
  int bm = blockIdx.x;   // 64
  int bn = blockIdx.y;   // 8
  f32x4 acc[4][4] = {};
  gemm128_core(xat + (size_t)bm * 128 * H_,
               w16 + (size_t)3 * H_ * H_ + (size_t)bn * 128 * H_, H_,
               ldsA, ldsB, acc);
  int l = threadIdx.x & 63, w = threadIdx.x >> 6;
  int wm = (w >> 1) * 64, wn = (w & 1) * 64;
  int col0 = bn * 128 + wn;
  int row0 = bm * 128 + wm;
  int b = row0 >> 10;
  const float* wdc = dc + (size_t)3 * B_ * H_ + b * H_;
  const float* udc = dc + (size_t)4 * B_ * H_ + b * H_;
  float ratio[4], ud[4];
#pragma unroll
  for (int ni = 0; ni < 4; ni++) {
    int col = col0 + ni * 16 + (l & 15);
    ud[ni] = udc[col];
    ratio[ni] = wdc[col] / ud[ni];
  }
#pragma unroll
  for (int mi = 0; mi < 4; mi++)
#pragma unroll
    for (int ni = 0; ni < 4; ni++)
#pragma unroll
      for (int rr = 0; rr < 4; rr++) acc[mi][ni][rr] *= ratio[ni];
  gemm128_core(vfl + (size_t)bm * 128 * H_,
               w16 + (size_t)4 * H_ * H_ + (size_t)bn * 128 * H_, H_,
               ldsA, ldsB, acc);
#pragma unroll
  for (int mi = 0; mi < 4; mi++)
#pragma unroll
    for (int ni = 0; ni < 4; ni++) {
      int col = col0 + ni * 16 + (l & 15);
#pragma unroll
      for (int rr = 0; rr < 4; rr++) {
        int row = row0 + mi * 16 + (l >> 4) * 4 + rr;
        out[(size_t)row * H_ + col] = acc[mi][ni][rr] * ud[ni];
      }
    }
}

extern "C" void kernel_launch(void* const* d_in, const int* in_sizes, int n_in,
                              void* d_out, int out_size, void* d_ws, size_t ws_size,
                              hipStream_t stream) {
  const float* x = (const float*)d_in[0];
  const float* qw = (const float*)d_in[1];
  const float* kw = (const float*)d_in[2];
  const float* vw = (const float*)d_in[3];
  const float* ww = (const float*)d_in[4];
  const float* uw = (const float*)d_in[5];
  const float* styles = (const float*)d_in[6];
  float* out = (float*)d_out;

  char* ws = (char*)d_ws;
  size_t need = 163840 + (size_t)5 * H_ * H_ * 2 + (size_t)6 * BS * H_ * 2;
  if (ws_size < need) return;
  float* dc = (float*)ws;
  u16* w16 = (u16*)(ws + 163840);
  u16* xn  = w16 + (size_t)5 * H_ * H_;
  u16* Qb  = xn + (size_t)BS * H_;
  u16* Kb  = Qb + (size_t)BS * H_;
  u16* VT  = Kb + (size_t)BS * H_;
  u16* vfl = VT + (size_t)BS * H_;
  u16* xat = vfl + (size_t)BS * H_;

  prep_kernel<<<dim3(5120 + BS), dim3(256), 0, stream>>>(
      qw, kw, vw, ww, uw, styles, x, dc, w16, xn);
  qkv_kernel<<<dim3(64, 24), dim3(256), 0, stream>>>(xn, w16, dc, Qb, Kb, VT, vfl);
  attn_kernel<<<dim3(512), dim3(512), 0, stream>>>(Qb, Kb, VT, xat);
  out_kernel<<<dim3(64, 8), dim3(256), 0, stream>>>(xat, vfl, w16, dc, out);
}